// Round 11
// baseline (269.246 us; speedup 1.0000x reference)
//
#include <hip/hip_runtime.h>

// Shapes: B=64, N=197, C=768, H=12, hd=64
// qkv/proj GEMM: plain bf16 (K=768), 128x256 tile (acc[4][8]), XCD-chunked
//   bijective swizzle, qkv epilogue via per-wave LDS transpose. (r9, measured)
// Attention: K from global with FORCED batched loads -- 13 bias + 13 K-frag
//   loads issued, then sched_barrier(0), then 13 MFMAs (x2 halves). r5's
//   unforced attempt was sunk by the scheduler (VGPR stayed 84); the fence
//   makes the compiler keep ~13 loads in flight (VGPR should read ~140).
//   VS=212 stride kept (bank conflicts 1.3M -> 0, measured r10).
//   LDS 54272 B -> 3 blocks/CU, 768 blocks co-resident.
// prepare = fused convert + bias gather.

#define NB   64
#define NN   197
#define NC   768
#define NH   12
#define HD   64
#define MM   (NB*NN)      // 12608
#define MR   12672        // 99*128
#define NP   208          // 13*16
#define VS   212          // Vt / P row stride (ushorts); 106 dwords == 10 mod 32
#define SZQ  ((size_t)NB * NH * NN * HD)
#define CVTQ ((MM + 2304 + 768) * 192)
#define BIASN (NH * 13 * 13 * 256)

typedef unsigned short ushort_t;
typedef __attribute__((ext_vector_type(8))) short short8;
typedef __attribute__((ext_vector_type(4))) float f32x4;
union U128 { uint4 u; short8 s; };

__device__ __forceinline__ unsigned bf16_rne(float f) {
    unsigned u = __float_as_uint(f);
    return (u + 0x7fffu + ((u >> 16) & 1u)) >> 16;
}

__device__ __forceinline__ void gld16(unsigned short* lds, const unsigned short* g) {
    __builtin_amdgcn_global_load_lds(
        (const __attribute__((address_space(1))) void*)g,
        (__attribute__((address_space(3))) void*)lds, 16, 0, 0);
}

// ---------------------------------------------------------------------------
// prepare: x->xh, w_qkv->wh, w_proj->wp (bf16) AND biasP fragment gather.
// ---------------------------------------------------------------------------
__global__ __launch_bounds__(256) void prepare(
    const float* __restrict__ x, const float* __restrict__ w_qkv,
    const float* __restrict__ w_proj, const float* __restrict__ table,
    const int* __restrict__ rel_index,
    ushort_t* __restrict__ xh, ushort_t* __restrict__ wh,
    ushort_t* __restrict__ wp, float* __restrict__ biasP)
{
    int idx = blockIdx.x * 256 + threadIdx.x;
    if (idx < CVTQ) {
        int r = idx / 192;
        int c = (idx - r * 192) * 4;
        const float* src;
        ushort_t* dsth;
        if (r < MM) {
            src = x + (size_t)r * NC; dsth = xh + (size_t)r * NC + c;
        } else if (r < MM + 2304) {
            int rr = r - MM;
            src = w_qkv + (size_t)rr * NC; dsth = wh + (size_t)rr * NC + c;
        } else {
            int rr = r - MM - 2304;
            src = w_proj + (size_t)rr * NC; dsth = wp + (size_t)rr * NC + c;
        }
        float4 f = *(const float4*)(src + c);
        ushort4 hv = { (ushort_t)bf16_rne(f.x), (ushort_t)bf16_rne(f.y),
                       (ushort_t)bf16_rne(f.z), (ushort_t)bf16_rne(f.w) };
        *(ushort4*)dsth = hv;
    } else {
        int i = idx - CVTQ;
        if (i < BIASN) {
            int r = i & 3, l15 = (i >> 2) & 15, quad = (i >> 6) & 3;
            int t = i >> 8;
            int kt = t % 13; int t2 = t / 13;
            int qt = t2 % 13; int h = t2 / 13;
            int n = qt * 16 + quad * 4 + r;
            int m = kt * 16 + l15;
            float v = -1e30f;
            if (n < NN && m < NN) v = table[rel_index[n * NN + m] * NH + h];
            biasP[i] = v;
        }
    }
}

// ---------------------------------------------------------------------------
// bf16 MFMA mainloop, 128(M) x 256(N) tile, 4 waves (wm=M-half, wn=N-half).
// ---------------------------------------------------------------------------
__device__ __forceinline__ void gemm_mainloop(
    const ushort_t* __restrict__ A2, int sA,
    const ushort_t* __restrict__ B2, int sB,
    int m0, int n0, int kiters, ushort_t* Abuf, ushort_t* Bbuf, f32x4 acc[4][8])
{
    const int tid = threadIdx.x;
    const int w = tid >> 6, lane = tid & 63;
    const int wm = w & 1, wn = w >> 1;
    const int lr = lane >> 3, lc = lane & 7;
    const int gch = lc ^ lr;

    const ushort_t* Ag = A2 + (size_t)(m0 + w * 32 + lr) * sA + gch * 8;
    const ushort_t* Bg = B2 + (size_t)(n0 + w * 64 + lr) * sB + gch * 8;
    ushort_t* Al = Abuf + (w * 32) * 64;
    ushort_t* Bl = Bbuf + (w * 64) * 64;

    int aoff[4], boff[8];
    const int quad = lane >> 4, l15 = lane & 15;
    #pragma unroll
    for (int t = 0; t < 4; t++) {
        int ra = wm * 64 + t * 16 + l15;
        aoff[t] = ra * 64 + ((quad ^ (ra & 7)) << 3);
    }
    #pragma unroll
    for (int j = 0; j < 8; j++) {
        int rb = wn * 128 + j * 16 + l15;
        boff[j] = rb * 64 + ((quad ^ (rb & 7)) << 3);
    }

    for (int ks = 0; ks < kiters; ks++) {
        __syncthreads();
        #pragma unroll
        for (int it = 0; it < 4; it++)
            gld16(Al + it * 8 * 64, Ag + (size_t)it * 8 * sA);
        #pragma unroll
        for (int it = 0; it < 8; it++)
            gld16(Bl + it * 8 * 64, Bg + (size_t)it * 8 * sB);
        __syncthreads();
        #pragma unroll
        for (int k0 = 0; k0 < 2; k0++) {
            U128 af[4], bf[8];
            #pragma unroll
            for (int t = 0; t < 4; t++)
                af[t].u = *(const uint4*)&Abuf[aoff[t] ^ (k0 << 5)];
            #pragma unroll
            for (int j = 0; j < 8; j++)
                bf[j].u = *(const uint4*)&Bbuf[boff[j] ^ (k0 << 5)];
            #pragma unroll
            for (int i = 0; i < 4; i++)
                #pragma unroll
                for (int j = 0; j < 8; j++)
                    acc[i][j] = __builtin_amdgcn_mfma_f32_16x16x32_bf16(
                        af[i].s, bf[j].s, acc[i][j], 0, 0, 0);
        }
        Ag += 64; Bg += 64;
    }
}

// XCD-bijective chunked remap: consecutive f within one XCD.
__device__ __forceinline__ int xcd_remap(int bid, int nwg) {
    int q8 = nwg >> 3, r8 = nwg & 7;
    int xcd = bid & 7, loc = bid >> 3;
    return (xcd < r8 ? xcd * (q8 + 1) : r8 * (q8 + 1) + (xcd - r8) * q8) + loc;
}

// GEMM1: xh[MR,768] * wh[2304,768]^T -> qbf (scaled), kbf, vbf. 891 blocks.
__global__ __launch_bounds__(256, 2) void gemm_qkv_mfma(
    const ushort_t* __restrict__ A2, const ushort_t* __restrict__ B2,
    ushort_t* __restrict__ qbf, ushort_t* __restrict__ kbf,
    ushort_t* __restrict__ vbf)
{
    __shared__ ushort_t Abuf[128 * 64];
    __shared__ ushort_t Bbuf[256 * 64];
    f32x4 acc[4][8];
    f32x4 z = {0.f, 0.f, 0.f, 0.f};
    #pragma unroll
    for (int i = 0; i < 4; i++)
        #pragma unroll
        for (int j = 0; j < 8; j++) acc[i][j] = z;

    int f = xcd_remap(blockIdx.x, 891);
    int mt_ = f / 9, nt_ = f - mt_ * 9;
    const int m0 = mt_ * 128, n0 = nt_ * 256;
    gemm_mainloop(A2, NC, B2, NC, m0, n0, 12, Abuf, Bbuf, acc);

    __syncthreads();                         // Abuf free for reuse as scratch

    const int tid = threadIdx.x;
    const int w = tid >> 6, lane = tid & 63;
    const int wm = w & 1, wn = w >> 1;
    const int quad = lane >> 4, l15 = lane & 15;

    ushort_t* Sw = Abuf + w * 1152;
    const int orow = lane >> 2;
    const int dch = (lane & 3) << 3;
    #pragma unroll
    for (int mt = 0; mt < 4; mt++) {
        int m = m0 + wm * 64 + mt * 16 + orow;
        int b_ = m / NN, n_ = m - b_ * NN;
        bool mv = (m < MM);
        #pragma unroll
        for (int g = 0; g < 2; g++) {
            int cg = n0 + wn * 128 + g * 64;
            int tq = cg / NC;
            int wi = cg - tq * NC;
            int hh = wi >> 6;
            ushort_t* dst = (tq == 0) ? qbf : (tq == 1) ? kbf : vbf;
            float scale = (tq == 0) ? 0.125f : 1.0f;
            #pragma unroll
            for (int nt = 0; nt < 4; nt++)
                #pragma unroll
                for (int r = 0; r < 4; r++)
                    Sw[(quad * 4 + r) * 72 + nt * 16 + l15] =
                        (ushort_t)bf16_rne(acc[mt][g * 4 + nt][r] * scale);
            if (mv) {
                size_t rb = ((size_t)(b_ * NH + hh) * NN + n_) * HD;
                uint4 v0 = *(const uint4*)&Sw[orow * 72 + dch];
                uint4 v1 = *(const uint4*)&Sw[orow * 72 + dch + 32];
                *(uint4*)&dst[rb + dch] = v0;
                *(uint4*)&dst[rb + dch + 32] = v1;
            }
        }
    }
}

// GEMM2: ab[MR,768] * wp[768,768]^T + bias -> out fp32. 297 blocks.
__global__ __launch_bounds__(256, 2) void gemm_proj_mfma(
    const ushort_t* __restrict__ A2, const ushort_t* __restrict__ B2,
    const float* __restrict__ bias, float* __restrict__ out)
{
    __shared__ ushort_t Abuf[128 * 64];
    __shared__ ushort_t Bbuf[256 * 64];
    f32x4 acc[4][8];
    f32x4 z = {0.f, 0.f, 0.f, 0.f};
    #pragma unroll
    for (int i = 0; i < 4; i++)
        #pragma unroll
        for (int j = 0; j < 8; j++) acc[i][j] = z;

    int f = xcd_remap(blockIdx.x, 297);
    int mt_ = f / 3, nt_ = f - mt_ * 3;
    const int m0 = mt_ * 128, n0 = nt_ * 256;
    gemm_mainloop(A2, NC, B2, NC, m0, n0, 12, Abuf, Bbuf, acc);

    const int tid = threadIdx.x;
    const int w = tid >> 6, lane = tid & 63;
    const int wm = w & 1, wn = w >> 1;
    const int quad = lane >> 4, l15 = lane & 15;
    #pragma unroll
    for (int nt = 0; nt < 8; nt++) {
        int col = n0 + wn * 128 + nt * 16 + l15;
        float bi = bias[col];
        #pragma unroll
        for (int mt = 0; mt < 4; mt++) {
            #pragma unroll
            for (int r = 0; r < 4; r++) {
                int m = m0 + wm * 64 + mt * 16 + quad * 4 + r;
                if (m < MM)
                    out[(size_t)m * NC + col] = acc[mt][nt][r] + bi;
            }
        }
    }
}

// ---------------------------------------------------------------------------
// MFMA attention. grid 768 x 256 threads (4 waves). One block per (b,h).
// K from global, loads FORCE-batched via sched_barrier(0). VS=212 strides.
// LDS 54272 B -> 3 blocks/CU, all 768 blocks co-resident in one round.
// ---------------------------------------------------------------------------
__global__ __launch_bounds__(256, 3) void attn_mfma(
    const ushort_t* __restrict__ qbf, const ushort_t* __restrict__ kbf,
    const ushort_t* __restrict__ vbf, const float* __restrict__ biasP,
    ushort_t* __restrict__ ab)
{
    __shared__ ushort_t Vt[64 * VS];         // Vt[d][key], 27136 B
    __shared__ ushort_t Pl[4][16 * VS];      // per-wave P / V-stage / O-transpose

    const int bh = blockIdx.x;
    const int b = bh / NH, h = bh % NH;
    const int tid = threadIdx.x;
    const int w = tid >> 6, lane = tid & 63;
    const int quad = lane >> 4, l15 = lane & 15;
    const size_t base = (size_t)bh * (NN * HD);
    const ushort_t* kg = kbf + base;
    const ushort_t* vg = vbf + base;
    const ushort_t* qg = qbf + base;

    // stage V row-major coalesced, then LDS->LDS transpose into Vt
    ushort_t* Vstage = &Pl[0][0];            // 208*64 = 13312 <= 4*16*212
    for (int idx = tid; idx < NP * 8; idx += 256) {
        int row = idx >> 3, ch = idx & 7;
        uint4 val = {0u, 0u, 0u, 0u};
        if (row < NN) val = *(const uint4*)(vg + (size_t)row * HD + ch * 8);
        *(uint4*)&Vstage[row * HD + ch * 8] = val;
    }
    __syncthreads();
    for (int task = tid; task < 64 * 26; task += 256) {
        int d = task & 63, kc = task >> 6;   // kc 0..25, keys < 208
        ushort_t tmp[8];
        #pragma unroll
        for (int j = 0; j < 8; j++)
            tmp[j] = Vstage[(kc * 8 + j) * HD + d];
        uint4 u;
        u.x = (unsigned)tmp[0] | ((unsigned)tmp[1] << 16);
        u.y = (unsigned)tmp[2] | ((unsigned)tmp[3] << 16);
        u.z = (unsigned)tmp[4] | ((unsigned)tmp[5] << 16);
        u.w = (unsigned)tmp[6] | ((unsigned)tmp[7] << 16);
        *(uint4*)&Vt[d * VS + kc * 8] = u;
    }
    __syncthreads();                         // Vt ready; Pl free

    #pragma unroll
    for (int rep = 0; rep < 4; rep++) {
        int qt = w + rep * 4;
        if (qt > 12) break;
        const int q0 = qt * 16;

        int qrow = q0 + l15; if (qrow > NN - 1) qrow = NN - 1;
        U128 qf0, qf1;
        qf0.u = *(const uint4*)(qg + (size_t)qrow * HD + quad * 8);
        qf1.u = *(const uint4*)(qg + (size_t)qrow * HD + 32 + quad * 8);

        // S init from biasP (13 float4) + K half-0 (13 uint4): ALL issued,
        // then a scheduler fence so none get sunk to their uses. In-order
        // return => first MFMA waits once, rest pipeline.
        f32x4 S[13];
        const float* bp = biasP + ((size_t)(h * 13 + qt) * 13) * 256 + (quad << 6) + (l15 << 2);
        #pragma unroll
        for (int kt = 0; kt < 13; kt++) {
            float4 bv = *(const float4*)(bp + kt * 256);
            S[kt][0] = bv.x; S[kt][1] = bv.y; S[kt][2] = bv.z; S[kt][3] = bv.w;
        }
        U128 kf[13];
        #pragma unroll
        for (int kt = 0; kt < 13; kt++) {
            int krow = kt * 16 + l15; if (krow > NN - 1) krow = NN - 1;
            kf[kt].u = *(const uint4*)(kg + (size_t)krow * HD + quad * 8);
        }
        __builtin_amdgcn_sched_barrier(0);
        #pragma unroll
        for (int kt = 0; kt < 13; kt++)
            S[kt] = __builtin_amdgcn_mfma_f32_16x16x32_bf16(qf0.s, kf[kt].s, S[kt], 0, 0, 0);
        // K half-1: same pattern
        #pragma unroll
        for (int kt = 0; kt < 13; kt++) {
            int krow = kt * 16 + l15; if (krow > NN - 1) krow = NN - 1;
            kf[kt].u = *(const uint4*)(kg + (size_t)krow * HD + 32 + quad * 8);
        }
        __builtin_amdgcn_sched_barrier(0);
        #pragma unroll
        for (int kt = 0; kt < 13; kt++)
            S[kt] = __builtin_amdgcn_mfma_f32_16x16x32_bf16(qf1.s, kf[kt].s, S[kt], 0, 0, 0);

        // softmax (rows quad*4+r over 16 l15 lanes x 13 tiles)
        ushort_t* P = Pl[w];
        #pragma unroll
        for (int r = 0; r < 4; r++) {
            float mx = S[0][r];
            #pragma unroll
            for (int kt = 1; kt < 13; kt++) mx = fmaxf(mx, S[kt][r]);
            mx = fmaxf(mx, __shfl_xor(mx, 1));
            mx = fmaxf(mx, __shfl_xor(mx, 2));
            mx = fmaxf(mx, __shfl_xor(mx, 4));
            mx = fmaxf(mx, __shfl_xor(mx, 8));
            float sum = 0.f;
            #pragma unroll
            for (int kt = 0; kt < 13; kt++) {
                float e = __expf(S[kt][r] - mx);
                S[kt][r] = e;
                sum += e;
            }
            sum += __shfl_xor(sum, 1);
            sum += __shfl_xor(sum, 2);
            sum += __shfl_xor(sum, 4);
            sum += __shfl_xor(sum, 8);
            float inv = 1.0f / sum;
            int prow = quad * 4 + r;
            #pragma unroll
            for (int kt = 0; kt < 13; kt++)
                P[prow * VS + kt * 16 + l15] = (ushort_t)bf16_rne(S[kt][r] * inv);
        }

        // PV: 7 chunks of 32 keys; chunk 6 keys 208..223 masked to 0.
        f32x4 O[4];
        f32x4 z4 = {0.f, 0.f, 0.f, 0.f};
        #pragma unroll
        for (int dt = 0; dt < 4; dt++) O[dt] = z4;
        #pragma unroll
        for (int ks = 0; ks < 7; ks++) {
            int pc = ks * 32 + quad * 8;
            bool vld = (pc < NP);
            int pcc = vld ? pc : 0;
            U128 pf;
            pf.u = *(const uint4*)&P[l15 * VS + pcc];
            if (!vld) { pf.u.x = 0u; pf.u.y = 0u; pf.u.z = 0u; pf.u.w = 0u; }
            #pragma unroll
            for (int dt = 0; dt < 4; dt++) {
                U128 vf;
                vf.u = *(const uint4*)&Vt[(dt * 16 + l15) * VS + pcc];
                O[dt] = __builtin_amdgcn_mfma_f32_16x16x32_bf16(pf.s, vf.s, O[dt], 0, 0, 0);
            }
        }

        // epilogue: transpose O through wave-private LDS, emit b128 bf16 hi
        float* Osh = (float*)&Pl[w][0];      // stride 68 floats
        #pragma unroll
        for (int dt = 0; dt < 4; dt++)
            #pragma unroll
            for (int r = 0; r < 4; r++)
                Osh[(quad * 4 + r) * 68 + dt * 16 + l15] = O[dt][r];
        int orow = lane >> 2;
        int d0 = (lane & 3) << 4;
        int q = q0 + orow;
        if (q < NN) {
            unsigned hiw[8];
            #pragma unroll
            for (int k4 = 0; k4 < 4; k4++) {
                float4 f = *(const float4*)&Osh[orow * 68 + d0 + k4 * 4];
                unsigned h0 = bf16_rne(f.x), h1 = bf16_rne(f.y);
                unsigned h2 = bf16_rne(f.z), h3 = bf16_rne(f.w);
                hiw[k4 * 2]     = h0 | (h1 << 16);
                hiw[k4 * 2 + 1] = h2 | (h3 << 16);
            }
            size_t baseo = ((size_t)b * NN + q) * NC + h * HD + d0;
            uint4 hA = {hiw[0], hiw[1], hiw[2], hiw[3]};
            uint4 hB = {hiw[4], hiw[5], hiw[6], hiw[7]};
            *(uint4*)&ab[baseo] = hA;
            *(uint4*)&ab[baseo + 8] = hB;
        }
    }
}

// ---------------------------------------------------------------------------
extern "C" void kernel_launch(void* const* d_in, const int* in_sizes, int n_in,
                              void* d_out, int out_size, void* d_ws, size_t ws_size,
                              hipStream_t stream)
{
    const float* x        = (const float*)d_in[0];
    const float* table    = (const float*)d_in[1];
    const float* w_qkv    = (const float*)d_in[2];
    const float* w_proj   = (const float*)d_in[3];
    const float* b_proj   = (const float*)d_in[4];
    const int*   rel_idx  = (const int*)d_in[5];
    float* out = (float*)d_out;

    ushort_t* xh  = (ushort_t*)d_ws;                        // MR*768
    ushort_t* wh  = xh + (size_t)MR * NC;                   // 2304*768
    ushort_t* wp  = wh + (size_t)2304 * NC;                 // 768*768
    ushort_t* ab  = wp + (size_t)768 * NC;                  // MR*768
    ushort_t* qbf = ab + (size_t)MR * NC;                   // SZQ each
    ushort_t* kbf = qbf + SZQ;
    ushort_t* vbf = kbf + SZQ;
    float* biasP  = (float*)(vbf + SZQ);                    // BIASN f32

    const int ptot = CVTQ + BIASN;
    prepare<<<(ptot + 255) / 256, 256, 0, stream>>>(
        x, w_qkv, w_proj, table, rel_idx, xh, wh, wp, biasP);

    gemm_qkv_mfma<<<891, 256, 0, stream>>>(xh, wh, qbf, kbf, vbf);
    attn_mfma<<<768, 256, 0, stream>>>(qbf, kbf, vbf, biasP, ab);
    gemm_proj_mfma<<<297, 256, 0, stream>>>(ab, wp, b_proj, out);
}

// Round 12
// 234.225 us; speedup vs baseline: 1.1495x; 1.1495x over previous
//
#include <hip/hip_runtime.h>

// Shapes: B=64, N=197, C=768, H=12, hd=64
// qkv/proj GEMM: plain bf16 (K=768), 128x256 tile (acc[4][8]), XCD-chunked
//   bijective swizzle, qkv epilogue via per-wave LDS transpose. (r9, measured)
// Attention: combines the two isolated-measured wins:
//   (1) K staged in LDS w/ GEMM swizzle (r8: removes serial global K chain)
//   (2) VS=212 Vt/P strides (r10: PV bank conflicts 1.3M -> 0)
//   LDS 80896 B -> 2 blocks/CU. No sched_barrier (r11: forced spills,
//   WRITE_SIZE 18.9->49.6 MB -- falsified).
// prepare = fused convert + bias gather.

#define NB   64
#define NN   197
#define NC   768
#define NH   12
#define HD   64
#define MM   (NB*NN)      // 12608
#define MR   12672        // 99*128
#define NP   208          // 13*16
#define VS   212          // Vt / P row stride (ushorts); 106 dwords == 10 mod 32
#define SZQ  ((size_t)NB * NH * NN * HD)
#define CVTQ ((MM + 2304 + 768) * 192)
#define BIASN (NH * 13 * 13 * 256)

typedef unsigned short ushort_t;
typedef __attribute__((ext_vector_type(8))) short short8;
typedef __attribute__((ext_vector_type(4))) float f32x4;
union U128 { uint4 u; short8 s; };

__device__ __forceinline__ unsigned bf16_rne(float f) {
    unsigned u = __float_as_uint(f);
    return (u + 0x7fffu + ((u >> 16) & 1u)) >> 16;
}

__device__ __forceinline__ void gld16(unsigned short* lds, const unsigned short* g) {
    __builtin_amdgcn_global_load_lds(
        (const __attribute__((address_space(1))) void*)g,
        (__attribute__((address_space(3))) void*)lds, 16, 0, 0);
}

// ---------------------------------------------------------------------------
// prepare: x->xh, w_qkv->wh, w_proj->wp (bf16) AND biasP fragment gather.
// ---------------------------------------------------------------------------
__global__ __launch_bounds__(256) void prepare(
    const float* __restrict__ x, const float* __restrict__ w_qkv,
    const float* __restrict__ w_proj, const float* __restrict__ table,
    const int* __restrict__ rel_index,
    ushort_t* __restrict__ xh, ushort_t* __restrict__ wh,
    ushort_t* __restrict__ wp, float* __restrict__ biasP)
{
    int idx = blockIdx.x * 256 + threadIdx.x;
    if (idx < CVTQ) {
        int r = idx / 192;
        int c = (idx - r * 192) * 4;
        const float* src;
        ushort_t* dsth;
        if (r < MM) {
            src = x + (size_t)r * NC; dsth = xh + (size_t)r * NC + c;
        } else if (r < MM + 2304) {
            int rr = r - MM;
            src = w_qkv + (size_t)rr * NC; dsth = wh + (size_t)rr * NC + c;
        } else {
            int rr = r - MM - 2304;
            src = w_proj + (size_t)rr * NC; dsth = wp + (size_t)rr * NC + c;
        }
        float4 f = *(const float4*)(src + c);
        ushort4 hv = { (ushort_t)bf16_rne(f.x), (ushort_t)bf16_rne(f.y),
                       (ushort_t)bf16_rne(f.z), (ushort_t)bf16_rne(f.w) };
        *(ushort4*)dsth = hv;
    } else {
        int i = idx - CVTQ;
        if (i < BIASN) {
            int r = i & 3, l15 = (i >> 2) & 15, quad = (i >> 6) & 3;
            int t = i >> 8;
            int kt = t % 13; int t2 = t / 13;
            int qt = t2 % 13; int h = t2 / 13;
            int n = qt * 16 + quad * 4 + r;
            int m = kt * 16 + l15;
            float v = -1e30f;
            if (n < NN && m < NN) v = table[rel_index[n * NN + m] * NH + h];
            biasP[i] = v;
        }
    }
}

// ---------------------------------------------------------------------------
// bf16 MFMA mainloop, 128(M) x 256(N) tile, 4 waves (wm=M-half, wn=N-half).
// ---------------------------------------------------------------------------
__device__ __forceinline__ void gemm_mainloop(
    const ushort_t* __restrict__ A2, int sA,
    const ushort_t* __restrict__ B2, int sB,
    int m0, int n0, int kiters, ushort_t* Abuf, ushort_t* Bbuf, f32x4 acc[4][8])
{
    const int tid = threadIdx.x;
    const int w = tid >> 6, lane = tid & 63;
    const int wm = w & 1, wn = w >> 1;
    const int lr = lane >> 3, lc = lane & 7;
    const int gch = lc ^ lr;

    const ushort_t* Ag = A2 + (size_t)(m0 + w * 32 + lr) * sA + gch * 8;
    const ushort_t* Bg = B2 + (size_t)(n0 + w * 64 + lr) * sB + gch * 8;
    ushort_t* Al = Abuf + (w * 32) * 64;
    ushort_t* Bl = Bbuf + (w * 64) * 64;

    int aoff[4], boff[8];
    const int quad = lane >> 4, l15 = lane & 15;
    #pragma unroll
    for (int t = 0; t < 4; t++) {
        int ra = wm * 64 + t * 16 + l15;
        aoff[t] = ra * 64 + ((quad ^ (ra & 7)) << 3);
    }
    #pragma unroll
    for (int j = 0; j < 8; j++) {
        int rb = wn * 128 + j * 16 + l15;
        boff[j] = rb * 64 + ((quad ^ (rb & 7)) << 3);
    }

    for (int ks = 0; ks < kiters; ks++) {
        __syncthreads();
        #pragma unroll
        for (int it = 0; it < 4; it++)
            gld16(Al + it * 8 * 64, Ag + (size_t)it * 8 * sA);
        #pragma unroll
        for (int it = 0; it < 8; it++)
            gld16(Bl + it * 8 * 64, Bg + (size_t)it * 8 * sB);
        __syncthreads();
        #pragma unroll
        for (int k0 = 0; k0 < 2; k0++) {
            U128 af[4], bf[8];
            #pragma unroll
            for (int t = 0; t < 4; t++)
                af[t].u = *(const uint4*)&Abuf[aoff[t] ^ (k0 << 5)];
            #pragma unroll
            for (int j = 0; j < 8; j++)
                bf[j].u = *(const uint4*)&Bbuf[boff[j] ^ (k0 << 5)];
            #pragma unroll
            for (int i = 0; i < 4; i++)
                #pragma unroll
                for (int j = 0; j < 8; j++)
                    acc[i][j] = __builtin_amdgcn_mfma_f32_16x16x32_bf16(
                        af[i].s, bf[j].s, acc[i][j], 0, 0, 0);
        }
        Ag += 64; Bg += 64;
    }
}

// XCD-bijective chunked remap: consecutive f within one XCD.
__device__ __forceinline__ int xcd_remap(int bid, int nwg) {
    int q8 = nwg >> 3, r8 = nwg & 7;
    int xcd = bid & 7, loc = bid >> 3;
    return (xcd < r8 ? xcd * (q8 + 1) : r8 * (q8 + 1) + (xcd - r8) * q8) + loc;
}

// GEMM1: xh[MR,768] * wh[2304,768]^T -> qbf (scaled), kbf, vbf. 891 blocks.
__global__ __launch_bounds__(256, 2) void gemm_qkv_mfma(
    const ushort_t* __restrict__ A2, const ushort_t* __restrict__ B2,
    ushort_t* __restrict__ qbf, ushort_t* __restrict__ kbf,
    ushort_t* __restrict__ vbf)
{
    __shared__ ushort_t Abuf[128 * 64];
    __shared__ ushort_t Bbuf[256 * 64];
    f32x4 acc[4][8];
    f32x4 z = {0.f, 0.f, 0.f, 0.f};
    #pragma unroll
    for (int i = 0; i < 4; i++)
        #pragma unroll
        for (int j = 0; j < 8; j++) acc[i][j] = z;

    int f = xcd_remap(blockIdx.x, 891);
    int mt_ = f / 9, nt_ = f - mt_ * 9;
    const int m0 = mt_ * 128, n0 = nt_ * 256;
    gemm_mainloop(A2, NC, B2, NC, m0, n0, 12, Abuf, Bbuf, acc);

    __syncthreads();                         // Abuf free for reuse as scratch

    const int tid = threadIdx.x;
    const int w = tid >> 6, lane = tid & 63;
    const int wm = w & 1, wn = w >> 1;
    const int quad = lane >> 4, l15 = lane & 15;

    ushort_t* Sw = Abuf + w * 1152;
    const int orow = lane >> 2;
    const int dch = (lane & 3) << 3;
    #pragma unroll
    for (int mt = 0; mt < 4; mt++) {
        int m = m0 + wm * 64 + mt * 16 + orow;
        int b_ = m / NN, n_ = m - b_ * NN;
        bool mv = (m < MM);
        #pragma unroll
        for (int g = 0; g < 2; g++) {
            int cg = n0 + wn * 128 + g * 64;
            int tq = cg / NC;
            int wi = cg - tq * NC;
            int hh = wi >> 6;
            ushort_t* dst = (tq == 0) ? qbf : (tq == 1) ? kbf : vbf;
            float scale = (tq == 0) ? 0.125f : 1.0f;
            #pragma unroll
            for (int nt = 0; nt < 4; nt++)
                #pragma unroll
                for (int r = 0; r < 4; r++)
                    Sw[(quad * 4 + r) * 72 + nt * 16 + l15] =
                        (ushort_t)bf16_rne(acc[mt][g * 4 + nt][r] * scale);
            if (mv) {
                size_t rb = ((size_t)(b_ * NH + hh) * NN + n_) * HD;
                uint4 v0 = *(const uint4*)&Sw[orow * 72 + dch];
                uint4 v1 = *(const uint4*)&Sw[orow * 72 + dch + 32];
                *(uint4*)&dst[rb + dch] = v0;
                *(uint4*)&dst[rb + dch + 32] = v1;
            }
        }
    }
}

// GEMM2: ab[MR,768] * wp[768,768]^T + bias -> out fp32. 297 blocks.
__global__ __launch_bounds__(256, 2) void gemm_proj_mfma(
    const ushort_t* __restrict__ A2, const ushort_t* __restrict__ B2,
    const float* __restrict__ bias, float* __restrict__ out)
{
    __shared__ ushort_t Abuf[128 * 64];
    __shared__ ushort_t Bbuf[256 * 64];
    f32x4 acc[4][8];
    f32x4 z = {0.f, 0.f, 0.f, 0.f};
    #pragma unroll
    for (int i = 0; i < 4; i++)
        #pragma unroll
        for (int j = 0; j < 8; j++) acc[i][j] = z;

    int f = xcd_remap(blockIdx.x, 297);
    int mt_ = f / 3, nt_ = f - mt_ * 3;
    const int m0 = mt_ * 128, n0 = nt_ * 256;
    gemm_mainloop(A2, NC, B2, NC, m0, n0, 12, Abuf, Bbuf, acc);

    const int tid = threadIdx.x;
    const int w = tid >> 6, lane = tid & 63;
    const int wm = w & 1, wn = w >> 1;
    const int quad = lane >> 4, l15 = lane & 15;
    #pragma unroll
    for (int nt = 0; nt < 8; nt++) {
        int col = n0 + wn * 128 + nt * 16 + l15;
        float bi = bias[col];
        #pragma unroll
        for (int mt = 0; mt < 4; mt++) {
            #pragma unroll
            for (int r = 0; r < 4; r++) {
                int m = m0 + wm * 64 + mt * 16 + quad * 4 + r;
                if (m < MM)
                    out[(size_t)m * NC + col] = acc[mt][nt][r] + bi;
            }
        }
    }
}

// ---------------------------------------------------------------------------
// MFMA attention. grid 768 x 256 threads (4 waves). One block per (b,h).
// K reg-staged into swizzled LDS (r8); Vt/P strides 212 (r10, conflict-free).
// LDS 80896 B -> 2 blocks/CU.
// ---------------------------------------------------------------------------
__global__ __launch_bounds__(256) void attn_mfma(
    const ushort_t* __restrict__ qbf, const ushort_t* __restrict__ kbf,
    const ushort_t* __restrict__ vbf, const float* __restrict__ biasP,
    ushort_t* __restrict__ ab)
{
    __shared__ ushort_t Kl[NP * 64];         // 26624 B, GEMM-swizzle layout
    __shared__ ushort_t Vt[64 * VS];         // Vt[d][key], 27136 B
    __shared__ ushort_t Pl[4][16 * VS];      // per-wave P / V-stage / O-transpose

    const int bh = blockIdx.x;
    const int b = bh / NH, h = bh % NH;
    const int tid = threadIdx.x;
    const int w = tid >> 6, lane = tid & 63;
    const int quad = lane >> 4, l15 = lane & 15;
    const size_t base = (size_t)bh * (NN * HD);
    const ushort_t* kg = kbf + base;
    const ushort_t* vg = vbf + base;
    const ushort_t* qg = qbf + base;

    // ---- K stage: global -> reg -> swizzled LDS ----
    // Kl[row][slot s] = K[row][chunk s ^ (row&7)]; rows >= NN duplicate row
    // NN-1 (finite) -- neutralized by -1e30 bias in softmax.
    for (int idx = tid; idx < NP * 8; idx += 256) {
        int row = idx >> 3, ch = idx & 7;
        int srow = (row < NN) ? row : (NN - 1);
        uint4 val = *(const uint4*)(kg + (size_t)srow * HD + ch * 8);
        *(uint4*)&Kl[row * 64 + ((ch ^ (row & 7)) << 3)] = val;
    }

    // ---- stage V row-major coalesced, then LDS->LDS transpose into Vt ----
    ushort_t* Vstage = &Pl[0][0];            // 13312 ushorts <= 4*16*212
    for (int idx = tid; idx < NP * 8; idx += 256) {
        int row = idx >> 3, ch = idx & 7;
        uint4 val = {0u, 0u, 0u, 0u};
        if (row < NN) val = *(const uint4*)(vg + (size_t)row * HD + ch * 8);
        *(uint4*)&Vstage[row * HD + ch * 8] = val;
    }
    __syncthreads();                         // Kl + Vstage complete
    for (int task = tid; task < 64 * 26; task += 256) {
        int d = task & 63, kc = task >> 6;   // kc 0..25, keys < 208
        ushort_t tmp[8];
        #pragma unroll
        for (int j = 0; j < 8; j++)
            tmp[j] = Vstage[(kc * 8 + j) * HD + d];
        uint4 u;
        u.x = (unsigned)tmp[0] | ((unsigned)tmp[1] << 16);
        u.y = (unsigned)tmp[2] | ((unsigned)tmp[3] << 16);
        u.z = (unsigned)tmp[4] | ((unsigned)tmp[5] << 16);
        u.w = (unsigned)tmp[6] | ((unsigned)tmp[7] << 16);
        *(uint4*)&Vt[d * VS + kc * 8] = u;
    }
    __syncthreads();                         // Vt ready; Pl free

    const int ksl = (quad ^ (l15 & 7)) << 3; // K fragment slot (matches stage)

    #pragma unroll
    for (int rep = 0; rep < 4; rep++) {
        int qt = w + rep * 4;
        if (qt > 12) break;
        const int q0 = qt * 16;

        int qrow = q0 + l15; if (qrow > NN - 1) qrow = NN - 1;
        U128 qf0, qf1;
        qf0.u = *(const uint4*)(qg + (size_t)qrow * HD + quad * 8);
        qf1.u = *(const uint4*)(qg + (size_t)qrow * HD + 32 + quad * 8);

        // S init from biasP: 13 independent float4 loads
        f32x4 S[13];
        const float* bp = biasP + ((size_t)(h * 13 + qt) * 13) * 256 + (quad << 6) + (l15 << 2);
        #pragma unroll
        for (int kt = 0; kt < 13; kt++) {
            float4 bv = *(const float4*)(bp + kt * 256);
            S[kt][0] = bv.x; S[kt][1] = bv.y; S[kt][2] = bv.z; S[kt][3] = bv.w;
        }

        // QK^T: K fragments from LDS (conflict-free GEMM pattern)
        #pragma unroll
        for (int kt = 0; kt < 13; kt++) {
            int ro = (kt * 16 + l15) * 64 + ksl;
            U128 k0, k1;
            k0.u = *(const uint4*)&Kl[ro];
            k1.u = *(const uint4*)&Kl[ro ^ 32];
            S[kt] = __builtin_amdgcn_mfma_f32_16x16x32_bf16(qf0.s, k0.s, S[kt], 0, 0, 0);
            S[kt] = __builtin_amdgcn_mfma_f32_16x16x32_bf16(qf1.s, k1.s, S[kt], 0, 0, 0);
        }

        // softmax (rows quad*4+r over 16 l15 lanes x 13 tiles)
        ushort_t* P = Pl[w];
        #pragma unroll
        for (int r = 0; r < 4; r++) {
            float mx = S[0][r];
            #pragma unroll
            for (int kt = 1; kt < 13; kt++) mx = fmaxf(mx, S[kt][r]);
            mx = fmaxf(mx, __shfl_xor(mx, 1));
            mx = fmaxf(mx, __shfl_xor(mx, 2));
            mx = fmaxf(mx, __shfl_xor(mx, 4));
            mx = fmaxf(mx, __shfl_xor(mx, 8));
            float sum = 0.f;
            #pragma unroll
            for (int kt = 0; kt < 13; kt++) {
                float e = __expf(S[kt][r] - mx);
                S[kt][r] = e;
                sum += e;
            }
            sum += __shfl_xor(sum, 1);
            sum += __shfl_xor(sum, 2);
            sum += __shfl_xor(sum, 4);
            sum += __shfl_xor(sum, 8);
            float inv = 1.0f / sum;
            int prow = quad * 4 + r;
            #pragma unroll
            for (int kt = 0; kt < 13; kt++)
                P[prow * VS + kt * 16 + l15] = (ushort_t)bf16_rne(S[kt][r] * inv);
        }

        // PV: 7 chunks of 32 keys; chunk 6 keys 208..223 masked to 0.
        f32x4 O[4];
        f32x4 z4 = {0.f, 0.f, 0.f, 0.f};
        #pragma unroll
        for (int dt = 0; dt < 4; dt++) O[dt] = z4;
        #pragma unroll
        for (int ks = 0; ks < 7; ks++) {
            int pc = ks * 32 + quad * 8;
            bool vld = (pc < NP);
            int pcc = vld ? pc : 0;
            U128 pf;
            pf.u = *(const uint4*)&P[l15 * VS + pcc];
            if (!vld) { pf.u.x = 0u; pf.u.y = 0u; pf.u.z = 0u; pf.u.w = 0u; }
            #pragma unroll
            for (int dt = 0; dt < 4; dt++) {
                U128 vf;
                vf.u = *(const uint4*)&Vt[(dt * 16 + l15) * VS + pcc];
                O[dt] = __builtin_amdgcn_mfma_f32_16x16x32_bf16(pf.s, vf.s, O[dt], 0, 0, 0);
            }
        }

        // epilogue: transpose O through wave-private LDS, emit b128 bf16 hi
        float* Osh = (float*)&Pl[w][0];      // stride 68 floats
        #pragma unroll
        for (int dt = 0; dt < 4; dt++)
            #pragma unroll
            for (int r = 0; r < 4; r++)
                Osh[(quad * 4 + r) * 68 + dt * 16 + l15] = O[dt][r];
        int orow = lane >> 2;
        int d0 = (lane & 3) << 4;
        int q = q0 + orow;
        if (q < NN) {
            unsigned hiw[8];
            #pragma unroll
            for (int k4 = 0; k4 < 4; k4++) {
                float4 f = *(const float4*)&Osh[orow * 68 + d0 + k4 * 4];
                unsigned h0 = bf16_rne(f.x), h1 = bf16_rne(f.y);
                unsigned h2 = bf16_rne(f.z), h3 = bf16_rne(f.w);
                hiw[k4 * 2]     = h0 | (h1 << 16);
                hiw[k4 * 2 + 1] = h2 | (h3 << 16);
            }
            size_t baseo = ((size_t)b * NN + q) * NC + h * HD + d0;
            uint4 hA = {hiw[0], hiw[1], hiw[2], hiw[3]};
            uint4 hB = {hiw[4], hiw[5], hiw[6], hiw[7]};
            *(uint4*)&ab[baseo] = hA;
            *(uint4*)&ab[baseo + 8] = hB;
        }
    }
}

// ---------------------------------------------------------------------------
extern "C" void kernel_launch(void* const* d_in, const int* in_sizes, int n_in,
                              void* d_out, int out_size, void* d_ws, size_t ws_size,
                              hipStream_t stream)
{
    const float* x        = (const float*)d_in[0];
    const float* table    = (const float*)d_in[1];
    const float* w_qkv    = (const float*)d_in[2];
    const float* w_proj   = (const float*)d_in[3];
    const float* b_proj   = (const float*)d_in[4];
    const int*   rel_idx  = (const int*)d_in[5];
    float* out = (float*)d_out;

    ushort_t* xh  = (ushort_t*)d_ws;                        // MR*768
    ushort_t* wh  = xh + (size_t)MR * NC;                   // 2304*768
    ushort_t* wp  = wh + (size_t)2304 * NC;                 // 768*768
    ushort_t* ab  = wp + (size_t)768 * NC;                  // MR*768
    ushort_t* qbf = ab + (size_t)MR * NC;                   // SZQ each
    ushort_t* kbf = qbf + SZQ;
    ushort_t* vbf = kbf + SZQ;
    float* biasP  = (float*)(vbf + SZQ);                    // BIASN f32

    const int ptot = CVTQ + BIASN;
    prepare<<<(ptot + 255) / 256, 256, 0, stream>>>(
        x, w_qkv, w_proj, table, rel_idx, xh, wh, wp, biasP);

    gemm_qkv_mfma<<<891, 256, 0, stream>>>(xh, wh, qbf, kbf, vbf);
    attn_mfma<<<768, 256, 0, stream>>>(qbf, kbf, vbf, biasP, ab);
    gemm_proj_mfma<<<297, 256, 0, stream>>>(ab, wp, b_proj, out);
}

// Round 13
// 229.974 us; speedup vs baseline: 1.1708x; 1.0185x over previous
//
#include <hip/hip_runtime.h>

// Shapes: B=64, N=197, C=768, H=12, hd=64
// qkv/proj GEMM: plain bf16 (K=768), 128x256 tile (acc[4][8]), XCD-chunked
//   bijective swizzle, qkv epilogue via per-wave LDS transpose. (r9, measured)
// Attention: r12 base (Kl swizzled K-in-LDS + VS=212 conflict-free strides,
//   both measured) + PAIRED q-tiles per wave: tiles A,B share K/V fragments
//   (1 ds_read pair -> 4 MFMAs, 2 independent chains) and SM_B VALU overlaps
//   PV_A MFMA. launch_bounds(256,2) for ~170 VGPR headroom (LDS already caps
//   at 2 blocks/CU); r11's spill mode guarded by WRITE_SIZE tripwire.
// prepare = fused convert + bias gather.

#define NB   64
#define NN   197
#define NC   768
#define NH   12
#define HD   64
#define MM   (NB*NN)      // 12608
#define MR   12672        // 99*128
#define NP   208          // 13*16
#define VS   212          // Vt / P row stride (ushorts); 106 dwords == 10 mod 32
#define SZQ  ((size_t)NB * NH * NN * HD)
#define CVTQ ((MM + 2304 + 768) * 192)
#define BIASN (NH * 13 * 13 * 256)

typedef unsigned short ushort_t;
typedef __attribute__((ext_vector_type(8))) short short8;
typedef __attribute__((ext_vector_type(4))) float f32x4;
union U128 { uint4 u; short8 s; };

__device__ __forceinline__ unsigned bf16_rne(float f) {
    unsigned u = __float_as_uint(f);
    return (u + 0x7fffu + ((u >> 16) & 1u)) >> 16;
}

__device__ __forceinline__ void gld16(unsigned short* lds, const unsigned short* g) {
    __builtin_amdgcn_global_load_lds(
        (const __attribute__((address_space(1))) void*)g,
        (__attribute__((address_space(3))) void*)lds, 16, 0, 0);
}

// ---------------------------------------------------------------------------
// prepare: x->xh, w_qkv->wh, w_proj->wp (bf16) AND biasP fragment gather.
// ---------------------------------------------------------------------------
__global__ __launch_bounds__(256) void prepare(
    const float* __restrict__ x, const float* __restrict__ w_qkv,
    const float* __restrict__ w_proj, const float* __restrict__ table,
    const int* __restrict__ rel_index,
    ushort_t* __restrict__ xh, ushort_t* __restrict__ wh,
    ushort_t* __restrict__ wp, float* __restrict__ biasP)
{
    int idx = blockIdx.x * 256 + threadIdx.x;
    if (idx < CVTQ) {
        int r = idx / 192;
        int c = (idx - r * 192) * 4;
        const float* src;
        ushort_t* dsth;
        if (r < MM) {
            src = x + (size_t)r * NC; dsth = xh + (size_t)r * NC + c;
        } else if (r < MM + 2304) {
            int rr = r - MM;
            src = w_qkv + (size_t)rr * NC; dsth = wh + (size_t)rr * NC + c;
        } else {
            int rr = r - MM - 2304;
            src = w_proj + (size_t)rr * NC; dsth = wp + (size_t)rr * NC + c;
        }
        float4 f = *(const float4*)(src + c);
        ushort4 hv = { (ushort_t)bf16_rne(f.x), (ushort_t)bf16_rne(f.y),
                       (ushort_t)bf16_rne(f.z), (ushort_t)bf16_rne(f.w) };
        *(ushort4*)dsth = hv;
    } else {
        int i = idx - CVTQ;
        if (i < BIASN) {
            int r = i & 3, l15 = (i >> 2) & 15, quad = (i >> 6) & 3;
            int t = i >> 8;
            int kt = t % 13; int t2 = t / 13;
            int qt = t2 % 13; int h = t2 / 13;
            int n = qt * 16 + quad * 4 + r;
            int m = kt * 16 + l15;
            float v = -1e30f;
            if (n < NN && m < NN) v = table[rel_index[n * NN + m] * NH + h];
            biasP[i] = v;
        }
    }
}

// ---------------------------------------------------------------------------
// bf16 MFMA mainloop, 128(M) x 256(N) tile, 4 waves (wm=M-half, wn=N-half).
// ---------------------------------------------------------------------------
__device__ __forceinline__ void gemm_mainloop(
    const ushort_t* __restrict__ A2, int sA,
    const ushort_t* __restrict__ B2, int sB,
    int m0, int n0, int kiters, ushort_t* Abuf, ushort_t* Bbuf, f32x4 acc[4][8])
{
    const int tid = threadIdx.x;
    const int w = tid >> 6, lane = tid & 63;
    const int wm = w & 1, wn = w >> 1;
    const int lr = lane >> 3, lc = lane & 7;
    const int gch = lc ^ lr;

    const ushort_t* Ag = A2 + (size_t)(m0 + w * 32 + lr) * sA + gch * 8;
    const ushort_t* Bg = B2 + (size_t)(n0 + w * 64 + lr) * sB + gch * 8;
    ushort_t* Al = Abuf + (w * 32) * 64;
    ushort_t* Bl = Bbuf + (w * 64) * 64;

    int aoff[4], boff[8];
    const int quad = lane >> 4, l15 = lane & 15;
    #pragma unroll
    for (int t = 0; t < 4; t++) {
        int ra = wm * 64 + t * 16 + l15;
        aoff[t] = ra * 64 + ((quad ^ (ra & 7)) << 3);
    }
    #pragma unroll
    for (int j = 0; j < 8; j++) {
        int rb = wn * 128 + j * 16 + l15;
        boff[j] = rb * 64 + ((quad ^ (rb & 7)) << 3);
    }

    for (int ks = 0; ks < kiters; ks++) {
        __syncthreads();
        #pragma unroll
        for (int it = 0; it < 4; it++)
            gld16(Al + it * 8 * 64, Ag + (size_t)it * 8 * sA);
        #pragma unroll
        for (int it = 0; it < 8; it++)
            gld16(Bl + it * 8 * 64, Bg + (size_t)it * 8 * sB);
        __syncthreads();
        #pragma unroll
        for (int k0 = 0; k0 < 2; k0++) {
            U128 af[4], bf[8];
            #pragma unroll
            for (int t = 0; t < 4; t++)
                af[t].u = *(const uint4*)&Abuf[aoff[t] ^ (k0 << 5)];
            #pragma unroll
            for (int j = 0; j < 8; j++)
                bf[j].u = *(const uint4*)&Bbuf[boff[j] ^ (k0 << 5)];
            #pragma unroll
            for (int i = 0; i < 4; i++)
                #pragma unroll
                for (int j = 0; j < 8; j++)
                    acc[i][j] = __builtin_amdgcn_mfma_f32_16x16x32_bf16(
                        af[i].s, bf[j].s, acc[i][j], 0, 0, 0);
        }
        Ag += 64; Bg += 64;
    }
}

// XCD-bijective chunked remap: consecutive f within one XCD.
__device__ __forceinline__ int xcd_remap(int bid, int nwg) {
    int q8 = nwg >> 3, r8 = nwg & 7;
    int xcd = bid & 7, loc = bid >> 3;
    return (xcd < r8 ? xcd * (q8 + 1) : r8 * (q8 + 1) + (xcd - r8) * q8) + loc;
}

// GEMM1: xh[MR,768] * wh[2304,768]^T -> qbf (scaled), kbf, vbf. 891 blocks.
__global__ __launch_bounds__(256, 2) void gemm_qkv_mfma(
    const ushort_t* __restrict__ A2, const ushort_t* __restrict__ B2,
    ushort_t* __restrict__ qbf, ushort_t* __restrict__ kbf,
    ushort_t* __restrict__ vbf)
{
    __shared__ ushort_t Abuf[128 * 64];
    __shared__ ushort_t Bbuf[256 * 64];
    f32x4 acc[4][8];
    f32x4 z = {0.f, 0.f, 0.f, 0.f};
    #pragma unroll
    for (int i = 0; i < 4; i++)
        #pragma unroll
        for (int j = 0; j < 8; j++) acc[i][j] = z;

    int f = xcd_remap(blockIdx.x, 891);
    int mt_ = f / 9, nt_ = f - mt_ * 9;
    const int m0 = mt_ * 128, n0 = nt_ * 256;
    gemm_mainloop(A2, NC, B2, NC, m0, n0, 12, Abuf, Bbuf, acc);

    __syncthreads();                         // Abuf free for reuse as scratch

    const int tid = threadIdx.x;
    const int w = tid >> 6, lane = tid & 63;
    const int wm = w & 1, wn = w >> 1;
    const int quad = lane >> 4, l15 = lane & 15;

    ushort_t* Sw = Abuf + w * 1152;
    const int orow = lane >> 2;
    const int dch = (lane & 3) << 3;
    #pragma unroll
    for (int mt = 0; mt < 4; mt++) {
        int m = m0 + wm * 64 + mt * 16 + orow;
        int b_ = m / NN, n_ = m - b_ * NN;
        bool mv = (m < MM);
        #pragma unroll
        for (int g = 0; g < 2; g++) {
            int cg = n0 + wn * 128 + g * 64;
            int tq = cg / NC;
            int wi = cg - tq * NC;
            int hh = wi >> 6;
            ushort_t* dst = (tq == 0) ? qbf : (tq == 1) ? kbf : vbf;
            float scale = (tq == 0) ? 0.125f : 1.0f;
            #pragma unroll
            for (int nt = 0; nt < 4; nt++)
                #pragma unroll
                for (int r = 0; r < 4; r++)
                    Sw[(quad * 4 + r) * 72 + nt * 16 + l15] =
                        (ushort_t)bf16_rne(acc[mt][g * 4 + nt][r] * scale);
            if (mv) {
                size_t rb = ((size_t)(b_ * NH + hh) * NN + n_) * HD;
                uint4 v0 = *(const uint4*)&Sw[orow * 72 + dch];
                uint4 v1 = *(const uint4*)&Sw[orow * 72 + dch + 32];
                *(uint4*)&dst[rb + dch] = v0;
                *(uint4*)&dst[rb + dch + 32] = v1;
            }
        }
    }
}

// GEMM2: ab[MR,768] * wp[768,768]^T + bias -> out fp32. 297 blocks.
__global__ __launch_bounds__(256, 2) void gemm_proj_mfma(
    const ushort_t* __restrict__ A2, const ushort_t* __restrict__ B2,
    const float* __restrict__ bias, float* __restrict__ out)
{
    __shared__ ushort_t Abuf[128 * 64];
    __shared__ ushort_t Bbuf[256 * 64];
    f32x4 acc[4][8];
    f32x4 z = {0.f, 0.f, 0.f, 0.f};
    #pragma unroll
    for (int i = 0; i < 4; i++)
        #pragma unroll
        for (int j = 0; j < 8; j++) acc[i][j] = z;

    int f = xcd_remap(blockIdx.x, 297);
    int mt_ = f / 3, nt_ = f - mt_ * 3;
    const int m0 = mt_ * 128, n0 = nt_ * 256;
    gemm_mainloop(A2, NC, B2, NC, m0, n0, 12, Abuf, Bbuf, acc);

    const int tid = threadIdx.x;
    const int w = tid >> 6, lane = tid & 63;
    const int wm = w & 1, wn = w >> 1;
    const int quad = lane >> 4, l15 = lane & 15;
    #pragma unroll
    for (int nt = 0; nt < 8; nt++) {
        int col = n0 + wn * 128 + nt * 16 + l15;
        float bi = bias[col];
        #pragma unroll
        for (int mt = 0; mt < 4; mt++) {
            #pragma unroll
            for (int r = 0; r < 4; r++) {
                int m = m0 + wm * 64 + mt * 16 + quad * 4 + r;
                if (m < MM)
                    out[(size_t)m * NC + col] = acc[mt][nt][r] + bi;
            }
        }
    }
}

// ---------------------------------------------------------------------------
// MFMA attention. grid 768 x 256 threads (4 waves). One block per (b,h).
// Paired q-tiles per wave: A=w+rep*8, B=A+4. K/V fragments shared between
// A and B; SM_B overlaps PV_A. K in swizzled LDS; VS=212 strides.
// LDS 80896 B -> 2 blocks/CU. launch_bounds(256,2) for VGPR headroom.
// ---------------------------------------------------------------------------
__global__ __launch_bounds__(256, 2) void attn_mfma(
    const ushort_t* __restrict__ qbf, const ushort_t* __restrict__ kbf,
    const ushort_t* __restrict__ vbf, const float* __restrict__ biasP,
    ushort_t* __restrict__ ab)
{
    __shared__ ushort_t Kl[NP * 64];         // 26624 B, GEMM-swizzle layout
    __shared__ ushort_t Vt[64 * VS];         // Vt[d][key], 27136 B
    __shared__ ushort_t Pl[4][16 * VS];      // per-wave P / V-stage / O-transpose

    const int bh = blockIdx.x;
    const int b = bh / NH, h = bh % NH;
    const int tid = threadIdx.x;
    const int w = tid >> 6, lane = tid & 63;
    const int quad = lane >> 4, l15 = lane & 15;
    const size_t base = (size_t)bh * (NN * HD);
    const ushort_t* kg = kbf + base;
    const ushort_t* vg = vbf + base;
    const ushort_t* qg = qbf + base;

    // ---- K stage: global -> reg -> swizzled LDS ----
    for (int idx = tid; idx < NP * 8; idx += 256) {
        int row = idx >> 3, ch = idx & 7;
        int srow = (row < NN) ? row : (NN - 1);
        uint4 val = *(const uint4*)(kg + (size_t)srow * HD + ch * 8);
        *(uint4*)&Kl[row * 64 + ((ch ^ (row & 7)) << 3)] = val;
    }

    // ---- stage V row-major coalesced, then LDS->LDS transpose into Vt ----
    ushort_t* Vstage = &Pl[0][0];            // 13312 ushorts <= 4*16*212
    for (int idx = tid; idx < NP * 8; idx += 256) {
        int row = idx >> 3, ch = idx & 7;
        uint4 val = {0u, 0u, 0u, 0u};
        if (row < NN) val = *(const uint4*)(vg + (size_t)row * HD + ch * 8);
        *(uint4*)&Vstage[row * HD + ch * 8] = val;
    }
    __syncthreads();                         // Kl + Vstage complete
    for (int task = tid; task < 64 * 26; task += 256) {
        int d = task & 63, kc = task >> 6;   // kc 0..25, keys < 208
        ushort_t tmp[8];
        #pragma unroll
        for (int j = 0; j < 8; j++)
            tmp[j] = Vstage[(kc * 8 + j) * HD + d];
        uint4 u;
        u.x = (unsigned)tmp[0] | ((unsigned)tmp[1] << 16);
        u.y = (unsigned)tmp[2] | ((unsigned)tmp[3] << 16);
        u.z = (unsigned)tmp[4] | ((unsigned)tmp[5] << 16);
        u.w = (unsigned)tmp[6] | ((unsigned)tmp[7] << 16);
        *(uint4*)&Vt[d * VS + kc * 8] = u;
    }
    __syncthreads();                         // Vt ready; Pl free

    const int ksl = (quad ^ (l15 & 7)) << 3; // K fragment slot (matches stage)
    ushort_t* P = Pl[w];

    #pragma unroll
    for (int rep = 0; rep < 2; rep++) {
        const int qtA = w + rep * 8;
        const int qtB = qtA + 4;
        const bool hasB = (qtB <= 12);       // wave-uniform

        // ---- tile A: Q frags + S init from bias ----
        const int q0A = qtA * 16;
        int qrA = q0A + l15; if (qrA > NN - 1) qrA = NN - 1;
        U128 qA0, qA1;
        qA0.u = *(const uint4*)(qg + (size_t)qrA * HD + quad * 8);
        qA1.u = *(const uint4*)(qg + (size_t)qrA * HD + 32 + quad * 8);
        f32x4 SA[13];
        const float* bpA = biasP + ((size_t)(h * 13 + qtA) * 13) * 256 + (quad << 6) + (l15 << 2);
        #pragma unroll
        for (int kt = 0; kt < 13; kt++) {
            float4 bv = *(const float4*)(bpA + kt * 256);
            SA[kt][0] = bv.x; SA[kt][1] = bv.y; SA[kt][2] = bv.z; SA[kt][3] = bv.w;
        }

        // ---- tile B (if any): Q frags + S init ----
        const int q0B = qtB * 16;
        U128 qB0, qB1;
        f32x4 SB[13];
        if (hasB) {
            int qrB = q0B + l15; if (qrB > NN - 1) qrB = NN - 1;
            qB0.u = *(const uint4*)(qg + (size_t)qrB * HD + quad * 8);
            qB1.u = *(const uint4*)(qg + (size_t)qrB * HD + 32 + quad * 8);
            const float* bpB = biasP + ((size_t)(h * 13 + qtB) * 13) * 256 + (quad << 6) + (l15 << 2);
            #pragma unroll
            for (int kt = 0; kt < 13; kt++) {
                float4 bv = *(const float4*)(bpB + kt * 256);
                SB[kt][0] = bv.x; SB[kt][1] = bv.y; SB[kt][2] = bv.z; SB[kt][3] = bv.w;
            }
        }

        // ---- QK^T: shared K fragments, 2 independent MFMA chains ----
        if (hasB) {
            #pragma unroll
            for (int kt = 0; kt < 13; kt++) {
                int ro = (kt * 16 + l15) * 64 + ksl;
                U128 k0, k1;
                k0.u = *(const uint4*)&Kl[ro];
                k1.u = *(const uint4*)&Kl[ro ^ 32];
                SA[kt] = __builtin_amdgcn_mfma_f32_16x16x32_bf16(qA0.s, k0.s, SA[kt], 0, 0, 0);
                SB[kt] = __builtin_amdgcn_mfma_f32_16x16x32_bf16(qB0.s, k0.s, SB[kt], 0, 0, 0);
                SA[kt] = __builtin_amdgcn_mfma_f32_16x16x32_bf16(qA1.s, k1.s, SA[kt], 0, 0, 0);
                SB[kt] = __builtin_amdgcn_mfma_f32_16x16x32_bf16(qB1.s, k1.s, SB[kt], 0, 0, 0);
            }
        } else {
            #pragma unroll
            for (int kt = 0; kt < 13; kt++) {
                int ro = (kt * 16 + l15) * 64 + ksl;
                U128 k0, k1;
                k0.u = *(const uint4*)&Kl[ro];
                k1.u = *(const uint4*)&Kl[ro ^ 32];
                SA[kt] = __builtin_amdgcn_mfma_f32_16x16x32_bf16(qA0.s, k0.s, SA[kt], 0, 0, 0);
                SA[kt] = __builtin_amdgcn_mfma_f32_16x16x32_bf16(qA1.s, k1.s, SA[kt], 0, 0, 0);
            }
        }

        // ---- SM_A + P_A store ----
        #pragma unroll
        for (int r = 0; r < 4; r++) {
            float mx = SA[0][r];
            #pragma unroll
            for (int kt = 1; kt < 13; kt++) mx = fmaxf(mx, SA[kt][r]);
            mx = fmaxf(mx, __shfl_xor(mx, 1));
            mx = fmaxf(mx, __shfl_xor(mx, 2));
            mx = fmaxf(mx, __shfl_xor(mx, 4));
            mx = fmaxf(mx, __shfl_xor(mx, 8));
            float sum = 0.f;
            #pragma unroll
            for (int kt = 0; kt < 13; kt++) {
                float e = __expf(SA[kt][r] - mx);
                SA[kt][r] = e;
                sum += e;
            }
            sum += __shfl_xor(sum, 1);
            sum += __shfl_xor(sum, 2);
            sum += __shfl_xor(sum, 4);
            sum += __shfl_xor(sum, 8);
            float inv = 1.0f / sum;
            int prow = quad * 4 + r;
            #pragma unroll
            for (int kt = 0; kt < 13; kt++)
                P[prow * VS + kt * 16 + l15] = (ushort_t)bf16_rne(SA[kt][r] * inv);
        }

        // ---- PV_A ----
        f32x4 OA[4];
        f32x4 z4 = {0.f, 0.f, 0.f, 0.f};
        #pragma unroll
        for (int dt = 0; dt < 4; dt++) OA[dt] = z4;
        #pragma unroll
        for (int ks = 0; ks < 7; ks++) {
            int pc = ks * 32 + quad * 8;
            bool vld = (pc < NP);
            int pcc = vld ? pc : 0;
            U128 pf;
            pf.u = *(const uint4*)&P[l15 * VS + pcc];
            if (!vld) { pf.u.x = 0u; pf.u.y = 0u; pf.u.z = 0u; pf.u.w = 0u; }
            #pragma unroll
            for (int dt = 0; dt < 4; dt++) {
                U128 vf;
                vf.u = *(const uint4*)&Vt[(dt * 16 + l15) * VS + pcc];
                OA[dt] = __builtin_amdgcn_mfma_f32_16x16x32_bf16(pf.s, vf.s, OA[dt], 0, 0, 0);
            }
        }

        // ---- SM_B (VALU; overlaps PV_A's MFMA stream) + P_B + PV_B ----
        f32x4 OB[4];
        if (hasB) {
            #pragma unroll
            for (int r = 0; r < 4; r++) {
                float mx = SB[0][r];
                #pragma unroll
                for (int kt = 1; kt < 13; kt++) mx = fmaxf(mx, SB[kt][r]);
                mx = fmaxf(mx, __shfl_xor(mx, 1));
                mx = fmaxf(mx, __shfl_xor(mx, 2));
                mx = fmaxf(mx, __shfl_xor(mx, 4));
                mx = fmaxf(mx, __shfl_xor(mx, 8));
                float sum = 0.f;
                #pragma unroll
                for (int kt = 0; kt < 13; kt++) {
                    float e = __expf(SB[kt][r] - mx);
                    SB[kt][r] = e;
                    sum += e;
                }
                sum += __shfl_xor(sum, 1);
                sum += __shfl_xor(sum, 2);
                sum += __shfl_xor(sum, 4);
                sum += __shfl_xor(sum, 8);
                float inv = 1.0f / sum;
                int prow = quad * 4 + r;
                #pragma unroll
                for (int kt = 0; kt < 13; kt++)
                    P[prow * VS + kt * 16 + l15] = (ushort_t)bf16_rne(SB[kt][r] * inv);
            }
            #pragma unroll
            for (int dt = 0; dt < 4; dt++) OB[dt] = z4;
            #pragma unroll
            for (int ks = 0; ks < 7; ks++) {
                int pc = ks * 32 + quad * 8;
                bool vld = (pc < NP);
                int pcc = vld ? pc : 0;
                U128 pf;
                pf.u = *(const uint4*)&P[l15 * VS + pcc];
                if (!vld) { pf.u.x = 0u; pf.u.y = 0u; pf.u.z = 0u; pf.u.w = 0u; }
                #pragma unroll
                for (int dt = 0; dt < 4; dt++) {
                    U128 vf;
                    vf.u = *(const uint4*)&Vt[(dt * 16 + l15) * VS + pcc];
                    OB[dt] = __builtin_amdgcn_mfma_f32_16x16x32_bf16(pf.s, vf.s, OB[dt], 0, 0, 0);
                }
            }
        }

        // ---- epilogue A (after PV_B: Osh reuses the P region) ----
        {
            float* Osh = (float*)&Pl[w][0];  // stride 68 floats
            #pragma unroll
            for (int dt = 0; dt < 4; dt++)
                #pragma unroll
                for (int r = 0; r < 4; r++)
                    Osh[(quad * 4 + r) * 68 + dt * 16 + l15] = OA[dt][r];
            int orow = lane >> 2;
            int d0 = (lane & 3) << 4;
            int q = q0A + orow;
            if (q < NN) {
                unsigned hiw[8];
                #pragma unroll
                for (int k4 = 0; k4 < 4; k4++) {
                    float4 f = *(const float4*)&Osh[orow * 68 + d0 + k4 * 4];
                    unsigned h0 = bf16_rne(f.x), h1 = bf16_rne(f.y);
                    unsigned h2 = bf16_rne(f.z), h3 = bf16_rne(f.w);
                    hiw[k4 * 2]     = h0 | (h1 << 16);
                    hiw[k4 * 2 + 1] = h2 | (h3 << 16);
                }
                size_t baseo = ((size_t)b * NN + q) * NC + h * HD + d0;
                uint4 hA = {hiw[0], hiw[1], hiw[2], hiw[3]};
                uint4 hB = {hiw[4], hiw[5], hiw[6], hiw[7]};
                *(uint4*)&ab[baseo] = hA;
                *(uint4*)&ab[baseo + 8] = hB;
            }
        }
        // ---- epilogue B ----
        if (hasB) {
            float* Osh = (float*)&Pl[w][0];
            #pragma unroll
            for (int dt = 0; dt < 4; dt++)
                #pragma unroll
                for (int r = 0; r < 4; r++)
                    Osh[(quad * 4 + r) * 68 + dt * 16 + l15] = OB[dt][r];
            int orow = lane >> 2;
            int d0 = (lane & 3) << 4;
            int q = q0B + orow;
            if (q < NN) {
                unsigned hiw[8];
                #pragma unroll
                for (int k4 = 0; k4 < 4; k4++) {
                    float4 f = *(const float4*)&Osh[orow * 68 + d0 + k4 * 4];
                    unsigned h0 = bf16_rne(f.x), h1 = bf16_rne(f.y);
                    unsigned h2 = bf16_rne(f.z), h3 = bf16_rne(f.w);
                    hiw[k4 * 2]     = h0 | (h1 << 16);
                    hiw[k4 * 2 + 1] = h2 | (h3 << 16);
                }
                size_t baseo = ((size_t)b * NN + q) * NC + h * HD + d0;
                uint4 hA = {hiw[0], hiw[1], hiw[2], hiw[3]};
                uint4 hB = {hiw[4], hiw[5], hiw[6], hiw[7]};
                *(uint4*)&ab[baseo] = hA;
                *(uint4*)&ab[baseo + 8] = hB;
            }
        }
    }
}

// ---------------------------------------------------------------------------
extern "C" void kernel_launch(void* const* d_in, const int* in_sizes, int n_in,
                              void* d_out, int out_size, void* d_ws, size_t ws_size,
                              hipStream_t stream)
{
    const float* x        = (const float*)d_in[0];
    const float* table    = (const float*)d_in[1];
    const float* w_qkv    = (const float*)d_in[2];
    const float* w_proj   = (const float*)d_in[3];
    const float* b_proj   = (const float*)d_in[4];
    const int*   rel_idx  = (const int*)d_in[5];
    float* out = (float*)d_out;

    ushort_t* xh  = (ushort_t*)d_ws;                        // MR*768
    ushort_t* wh  = xh + (size_t)MR * NC;                   // 2304*768
    ushort_t* wp  = wh + (size_t)2304 * NC;                 // 768*768
    ushort_t* ab  = wp + (size_t)768 * NC;                  // MR*768
    ushort_t* qbf = ab + (size_t)MR * NC;                   // SZQ each
    ushort_t* kbf = qbf + SZQ;
    ushort_t* vbf = kbf + SZQ;
    float* biasP  = (float*)(vbf + SZQ);                    // BIASN f32

    const int ptot = CVTQ + BIASN;
    prepare<<<(ptot + 255) / 256, 256, 0, stream>>>(
        x, w_qkv, w_proj, table, rel_idx, xh, wh, wp, biasP);

    gemm_qkv_mfma<<<891, 256, 0, stream>>>(xh, wh, qbf, kbf, vbf);
    attn_mfma<<<768, 256, 0, stream>>>(qbf, kbf, vbf, biasP, ab);
    gemm_proj_mfma<<<297, 256, 0, stream>>>(ab, wp, b_proj, out);
}